// Round 6
// baseline (27.904 us; speedup 1.0000x reference)
//
#include <hip/hip_runtime.h>

#define BLOCK  256
#define IPT    8                  // i's per thread (independent acc chains)
#define ITILE  (BLOCK * IPT)      // 2048 i's per block
#define TJ     32                 // j-chunk per block
#define SUB    8                  // float4 (2 j's) register-staged sub-chunk
#define TSCALE 32.0f              // > max possible |1 - pj + pi| (~9)
#define NBIN   20                 // targets in [0, 20)

// kernel 1: pure pair-tile blocks, exact multiple of 256 blocks, plain stores.
__global__ __launch_bounds__(BLOCK) void prl_pairs(
    const float* __restrict__ pred, const int* __restrict__ targ,
    int n, int gx, float* __restrict__ partials)
{
    // sj packs two j's: (q0, F0, q1, F1) where q = 1-pj, F = q + 32*tj - 32
    __shared__ float4 sj[TJ / 2];
    __shared__ float  wsum[BLOCK / 64];

    const int tid = threadIdx.x;
    const int bx  = blockIdx.x % gx;
    const int by  = blockIdx.x / gx;
    const int i0  = bx * ITILE;
    const int j0  = by * TJ;

    float pi[IPT], Ei[IPT], s[IPT];
    #pragma unroll
    for (int m = 0; m < IPT; ++m) {
        const int i = i0 + m * BLOCK + tid;
        if (i < n) {
            const float p = pred[i];
            pi[m] = p;
            Ei[m] = __fmaf_rn(-TSCALE, (float)targ[i], p);     // p - 32*t
        } else {
            pi[m] = 0.0f; Ei[m] = -1.0e9f;                     // never contributes
        }
        s[m] = 0.0f;
    }

    if (tid < TJ) {
        const int j = j0 + tid;
        float q, F;
        if (j < n) {
            const float pj = pred[j];
            q = 1.0f - pj;
            F = __fmaf_rn(TSCALE, (float)targ[j], q - TSCALE); // q + 32*t - 32
        } else {
            q = 0.0f; F = -1.0e9f;                             // never contributes
        }
        ((float2*)sj)[tid] = make_float2(q, F);
    }
    __syncthreads();

    #pragma unroll
    for (int sub = 0; sub < TJ / (2 * SUB); ++sub) {
        float4 r[SUB];
        #pragma unroll
        for (int k = 0; k < SUB; ++k) r[k] = sj[sub * SUB + k];   // ds_read_b128
        #pragma unroll
        for (int k = 0; k < SUB; ++k) {
            #pragma unroll
            for (int m = 0; m < IPT; ++m) {
                const float g = Ei[m] + r[k].y;        // x + 32*(tj-ti-1)
                const float x = pi[m] + r[k].x;        // 1 - (pj - pi)
                s[m] += fmaxf(fminf(g, x), 0.0f);      // hinge iff ti < tj
            }
            #pragma unroll
            for (int m = 0; m < IPT; ++m) {
                const float g = Ei[m] + r[k].w;
                const float x = pi[m] + r[k].z;
                s[m] += fmaxf(fminf(g, x), 0.0f);
            }
        }
    }

    float st = 0.0f;
    #pragma unroll
    for (int m = 0; m < IPT; ++m) st += s[m];
    #pragma unroll
    for (int off = 32; off; off >>= 1) st += __shfl_down(st, off);

    const int wave = tid >> 6;
    if ((tid & 63) == 0) wsum[wave] = st;
    __syncthreads();
    if (tid == 0) {
        float b = 0.0f;
        #pragma unroll
        for (int w = 0; w < BLOCK / 64; ++w) b += wsum[w];
        partials[blockIdx.x] = b;                      // plain store
    }
}

// kernel 2: ballot-popcount histogram + partial reduce + analytic count + divide.
__global__ __launch_bounds__(BLOCK) void prl_final(
    const float* __restrict__ partials, int npair,
    const int* __restrict__ targ, int n, float* __restrict__ out)
{
    __shared__ double wsum[BLOCK / 64];
    __shared__ int    whist[BLOCK / 64][NBIN];
    const int tid  = threadIdx.x;
    const int wave = tid >> 6;
    const int lane = tid & 63;

    // histogram via ballot-popcount (no atomics, uniform trip count)
    int c[NBIN];
    #pragma unroll
    for (int v = 0; v < NBIN; ++v) c[v] = 0;
    const int iters = (n + BLOCK - 1) / BLOCK;
    for (int it = 0; it < iters; ++it) {
        const int i = it * BLOCK + tid;
        const int t = (i < n) ? targ[i] : -1;
        #pragma unroll
        for (int v = 0; v < NBIN; ++v)
            c[v] += __popcll(__ballot(t == v));
    }
    if (lane == 0) {
        #pragma unroll
        for (int v = 0; v < NBIN; ++v) whist[wave][v] = c[v];
    }

    // reduce partial sums
    double s = 0.0;
    for (int i = tid; i < npair; i += BLOCK) s += (double)partials[i];
    #pragma unroll
    for (int off = 32; off; off >>= 1) s += __shfl_down(s, off);
    if (lane == 0) wsum[wave] = s;
    __syncthreads();

    if (tid == 0) {
        double tot = 0.0;
        #pragma unroll
        for (int w = 0; w < BLOCK / 64; ++w) tot += wsum[w];
        long long sq = 0;
        #pragma unroll
        for (int v = 0; v < NBIN; ++v) {
            long long h = 0;
            #pragma unroll
            for (int w = 0; w < BLOCK / 64; ++w) h += whist[w][v];
            sq += h * h;
        }
        const long long cnt = ((long long)n * (long long)n - sq) / 2;  // #(t_i<t_j)
        out[0] = (cnt > 0) ? (float)(tot / (double)cnt) : 0.0f;
    }
}

extern "C" void kernel_launch(void* const* d_in, const int* in_sizes, int n_in,
                              void* d_out, int out_size, void* d_ws, size_t ws_size,
                              hipStream_t stream) {
    const float* pred = (const float*)d_in[0];
    const int*   targ = (const int*)d_in[1];
    float*       out  = (float*)d_out;
    const int    n    = in_sizes[0];

    float* partials = (float*)d_ws;
    const int gx    = (n + ITILE - 1) / ITILE;   // 4    for n=8192
    const int gy    = (n + TJ - 1) / TJ;         // 256
    const int npair = gx * gy;                   // 1024 = exactly 4 blocks/CU

    prl_pairs<<<npair, BLOCK, 0, stream>>>(pred, targ, n, gx, partials);
    prl_final<<<1, BLOCK, 0, stream>>>(partials, npair, targ, n, out);
}

// Round 7
// 15.853 us; speedup vs baseline: 1.7601x; 1.7601x over previous
//
#include <hip/hip_runtime.h>

#define BLOCK  256
#define IPT    4                  // i's per thread (independent acc chains)
#define ITILE  (BLOCK * IPT)      // 1024 i's per block
#define TJ     64                 // j-chunk per block
#define SUB    16                 // float2 register-staged sub-chunk
#define TSCALE 32.0f              // > max possible |1 - pj + pi| (~9)
#define NHB    16                 // histogram blocks (placed first in grid)
#define NBIN   20                 // targets in [0, 20)

// kernel 1: blocks [0,NHB) histogram via ballot-popcount; blocks [NHB, NHB+npair)
// pair tiles. All outputs plain stores -> no memset / atomics anywhere.
__global__ __launch_bounds__(BLOCK) void prl_main(
    const float* __restrict__ pred, const int* __restrict__ targ,
    int n, int gx,
    float* __restrict__ partials,     // [npair]
    int*   __restrict__ hist)         // [NHB * NBIN]
{
    const int tid = threadIdx.x;

    if ((int)blockIdx.x < NHB) {
        // ---------- ballot-popcount histogram block (no atomics) ----------
        const int hb   = blockIdx.x;
        const int wave = tid >> 6;
        const int lane = tid & 63;

        int c[NBIN];
        #pragma unroll
        for (int v = 0; v < NBIN; ++v) c[v] = 0;

        const int CHUNK = NHB * BLOCK * 2;            // 8192: iters==1 for n=8192
        const int iters = (n + CHUNK - 1) / CHUNK;
        for (int it = 0; it < iters; ++it) {
            const int i0 = it * CHUNK + hb * BLOCK * 2 + tid * 2;
            const int t0 = (i0     < n) ? targ[i0]     : -1;
            const int t1 = (i0 + 1 < n) ? targ[i0 + 1] : -1;
            #pragma unroll
            for (int v = 0; v < NBIN; ++v)
                c[v] += __popcll(__ballot(t0 == v)) + __popcll(__ballot(t1 == v));
        }

        __shared__ int whist[BLOCK / 64][NBIN];
        if (lane == 0) {
            #pragma unroll
            for (int v = 0; v < NBIN; ++v) whist[wave][v] = c[v];
        }
        __syncthreads();
        if (tid < NBIN) {
            int h = 0;
            #pragma unroll
            for (int w = 0; w < BLOCK / 64; ++w) h += whist[w][tid];
            hist[hb * NBIN + tid] = h;                 // plain store
        }
    } else {
        // ---------- pair tile block ----------
        __shared__ float2 sj[TJ];            // (q = 1-pj, F = q + 32*tj - 32)
        __shared__ float  wsum[BLOCK / 64];
        const int id = blockIdx.x - NHB;
        const int bx = id % gx;
        const int by = id / gx;
        const int i0 = bx * ITILE;
        const int j0 = by * TJ;

        float pi[IPT], Ei[IPT], s[IPT];
        #pragma unroll
        for (int m = 0; m < IPT; ++m) {
            const int i = i0 + m * BLOCK + tid;
            if (i < n) {
                const float p = pred[i];
                pi[m] = p;
                Ei[m] = __fmaf_rn(-TSCALE, (float)targ[i], p);     // p - 32*t
            } else {
                pi[m] = 0.0f; Ei[m] = -1.0e9f;                     // never contributes
            }
            s[m] = 0.0f;
        }

        if (tid < TJ) {
            const int j = j0 + tid;
            float q, F;
            if (j < n) {
                const float pj = pred[j];
                q = 1.0f - pj;
                F = __fmaf_rn(TSCALE, (float)targ[j], q - TSCALE); // q + 32*t - 32
            } else {
                q = 0.0f; F = -1.0e9f;                             // never contributes
            }
            sj[tid] = make_float2(q, F);
        }
        __syncthreads();

        #pragma unroll
        for (int sub = 0; sub < TJ / SUB; ++sub) {
            float2 r[SUB];
            #pragma unroll
            for (int k = 0; k < SUB; ++k) r[k] = sj[sub * SUB + k];  // batched ds_reads
            #pragma unroll
            for (int k = 0; k < SUB; ++k) {
                const float qk = r[k].x;
                const float Fk = r[k].y;
                #pragma unroll
                for (int m = 0; m < IPT; ++m) {
                    const float g = Ei[m] + Fk;        // x + 32*(tj-ti-1)
                    const float x = pi[m] + qk;        // 1 - (pj - pi)
                    s[m] += fmaxf(fminf(g, x), 0.0f);  // hinge iff ti < tj
                }
            }
        }

        float st = 0.0f;
        #pragma unroll
        for (int m = 0; m < IPT; ++m) st += s[m];
        #pragma unroll
        for (int off = 32; off; off >>= 1) st += __shfl_down(st, off);

        const int wave = tid >> 6;
        if ((tid & 63) == 0) wsum[wave] = st;
        __syncthreads();
        if (tid == 0) {
            float b = 0.0f;
            #pragma unroll
            for (int w = 0; w < BLOCK / 64; ++w) b += wsum[w];
            partials[id] = b;                          // plain store
        }
    }
}

// kernel 2: tiny reduce + analytic count + divide.
__global__ __launch_bounds__(BLOCK) void prl_final(
    const float* __restrict__ partials, int npair,
    const int* __restrict__ hist, int n, float* __restrict__ out)
{
    __shared__ double wsum[BLOCK / 64];
    __shared__ int    hv[NBIN];
    const int tid = threadIdx.x;

    double s = 0.0;
    for (int i = tid; i < npair; i += BLOCK) s += (double)partials[i];
    #pragma unroll
    for (int off = 32; off; off >>= 1) s += __shfl_down(s, off);
    if ((tid & 63) == 0) wsum[tid >> 6] = s;

    if (tid < NBIN) {
        int h = 0;
        #pragma unroll
        for (int b = 0; b < NHB; ++b) h += hist[b * NBIN + tid];
        hv[tid] = h;
    }
    __syncthreads();

    if (tid == 0) {
        double tot = 0.0;
        #pragma unroll
        for (int w = 0; w < BLOCK / 64; ++w) tot += wsum[w];
        long long sq = 0;
        #pragma unroll
        for (int v = 0; v < NBIN; ++v) { const long long h = hv[v]; sq += h * h; }
        const long long cnt = ((long long)n * (long long)n - sq) / 2;  // #(t_i<t_j)
        out[0] = (cnt > 0) ? (float)(tot / (double)cnt) : 0.0f;
    }
}

extern "C" void kernel_launch(void* const* d_in, const int* in_sizes, int n_in,
                              void* d_out, int out_size, void* d_ws, size_t ws_size,
                              hipStream_t stream) {
    const float* pred = (const float*)d_in[0];
    const int*   targ = (const int*)d_in[1];
    float*       out  = (float*)d_out;
    const int    n    = in_sizes[0];

    const int gx    = (n + ITILE - 1) / ITILE;   // 8    for n=8192
    const int gy    = (n + TJ - 1) / TJ;         // 128
    const int npair = gx * gy;                   // 1024 = exactly 4 blocks/CU

    float* partials = (float*)d_ws;
    int*   hist     = (int*)((char*)d_ws + ((size_t)npair + 64) * sizeof(float));

    prl_main<<<NHB + npair, BLOCK, 0, stream>>>(pred, targ, n, gx, partials, hist);
    prl_final<<<1, BLOCK, 0, stream>>>(partials, npair, hist, n, out);
}